// Round 6
// baseline (228.277 us; speedup 1.0000x reference)
//
#include <hip/hip_runtime.h>

#define INV_N (1.0f / 4096.0f)

__device__ __forceinline__ void bf(float& ar, float& ai, float& br, float& bi,
                                   float s, float cs) {
    float tr = cs * br - s * bi;
    float ti = cs * bi + s * br;
    br = ar - tr; bi = ai - ti;
    ar = ar + tr; ai = ai + ti;
}

// Twiddle: angle = -2pi*(k/4096)*wk radians => rev = -(k/4096)*wk revolutions.
__device__ __forceinline__ void tw(int k, float wk, float* s, float* cs) {
    float rev = (float)k * (-INV_N) * wk;
    rev = __builtin_amdgcn_fractf(rev);          // [0,1), handles negatives
    *s  = __builtin_amdgcn_sinf(rev);            // sin(2*pi*rev)
    *cs = __builtin_amdgcn_cosf(rev);            // cos(2*pi*rev)
}

// Fused two-tile two-round 16 KB-per-tile ownership exchange:
// consecutive-16 rows -> stride-4 rows, parity predicate per round
// (pb + (m>>2) + (m&3)) & 1 (what a thread flushes in a round is exactly what
// it refills in that round). Both tiles share the 3 barriers.
__device__ __forceinline__ void exchange2(float2* tAp, float2* tBp,
                                          float (&arA)[16], float (&aiA)[16],
                                          float (&arB)[16], float (&aiB)[16],
                                          int pb, int c) {
#pragma unroll
    for (int par = 0; par < 2; ++par) {
#pragma unroll
        for (int m = 0; m < 16; ++m) {
            if (((pb + (m >> 2) + (m & 3)) & 1) == par) {
                int srow = (pb << 3) + (((m >> 2) << 1) | ((m & 3) >> 1));
                tAp[srow * 64 + c] = make_float2(arA[m], aiA[m]);
                tBp[srow * 64 + c] = make_float2(arB[m], aiB[m]);
            }
        }
        __syncthreads();
#pragma unroll
        for (int m = 0; m < 16; ++m) {
            if (((pb + (m >> 2) + (m & 3)) & 1) == par) {
                int srow = ((m >> 2) << 3) + ((m & 3) << 1) + (pb >> 1);
                float2 v = tAp[srow * 64 + c];
                arA[m] = v.x; aiA[m] = v.y;
                v = tBp[srow * 64 + c];
                arB[m] = v.x; aiB[m] = v.y;
            }
        }
        if (par == 0) __syncthreads();
    }
}

// Kernel A: stages step=2..64 (butterflies within aligned 64-row blocks).
// TWO column-tiles per block (cols c0..c0+63 and c0+64..c0+127): doubles
// per-wave MLP/ILP — all ~86 loads issue at entry, two independent compute
// chains interleave. Row-major I/O throughout (round-5 blocked layout was a
// regression — reverted). Grid 2048.
__global__ __launch_bounds__(256) void fft_lo(const float* __restrict__ x,
                                              const float* __restrict__ w,
                                              float2* __restrict__ dst2,
                                              unsigned dst_lim2) {
    __shared__ __align__(16) float2 tA[32 * 64];     // 16 KB
    __shared__ __align__(16) float2 tB[32 * 64];     // 16 KB
    const int t    = threadIdx.x;
    const int c    = t & 63;
    const int pb   = t >> 6;
    const int r0   = (blockIdx.x >> 5) << 6;
    const int src_r0 = r0 ^ 2048;    // initial permutation: new[i] = old[i^2048]
    const int col0 = ((blockIdx.x & 31) << 7) + c;
    const int col1 = col0 + 64;

    // ---- prefetch ALL w values for both tiles ----
    float wp1A[7], wp1B[7];
#pragma unroll
    for (int i = 0; i < 7; ++i) {
        size_t ro = (size_t)(256 * (i + 1)) * 4096;
        wp1A[i] = w[ro + col0]; wp1B[i] = w[ro + col1];
    }
    float w2aA[4], w2aB[4], w2bA[8], w2bB[8];
#pragma unroll
    for (int i = 0; i < 4; ++i) {
        size_t ro = (size_t)((pb + 4 * i) * 128) * 4096;
        w2aA[i] = w[ro + col0]; w2aB[i] = w[ro + col1];
    }
#pragma unroll
    for (int i = 0; i < 8; ++i) {
        size_t ro = (size_t)((pb + 4 * i) * 64) * 4096;
        w2bA[i] = w[ro + col0]; w2bB[i] = w[ro + col1];
    }

    // ---- direct loads: rows 16*pb+m for both tiles, imag = 0 ----
    float arA[16], aiA[16], arB[16], aiB[16];
#pragma unroll
    for (int m = 0; m < 16; ++m) {
        size_t ro = (size_t)(src_r0 + 16 * pb + m) * 4096;
        arA[m] = __builtin_nontemporal_load(&x[ro + col0]);
        arB[m] = __builtin_nontemporal_load(&x[ro + col1]);
        aiA[m] = 0.f; aiB[m] = 0.f;
    }

    // ---- phase-1 twiddles (k = 256*i; per tile) ----
    float s1A[8], c1A[8], s1B[8], c1B[8];
    s1A[0] = 0.f; c1A[0] = 1.f; s1B[0] = 0.f; c1B[0] = 1.f;
#pragma unroll
    for (int i = 1; i < 8; ++i) {
        tw(256 * i, wp1A[i - 1], &s1A[i], &c1A[i]);
        tw(256 * i, wp1B[i - 1], &s1B[i], &c1B[i]);
    }

    // ---- phase 1: h = 1,2,4,8 (steps 2..16); twiddle index = r*8/h ----
#pragma unroll
    for (int h = 1; h <= 8; h <<= 1) {
        const int step = h << 1;
#pragma unroll
        for (int r = 0; r < h; ++r) {
            const int ti = r * (8 / h);
#pragma unroll
            for (int b = 0; b < 8 / h; ++b) {
                const int mt = b * step + r;
                bf(arA[mt], aiA[mt], arA[mt + h], aiA[mt + h], s1A[ti], c1A[ti]);
                bf(arB[mt], aiB[mt], arB[mt + h], aiB[mt + h], s1B[ti], c1B[ti]);
            }
        }
    }

    // ---- phase-2 twiddles BEFORE the barriers ----
    float s2aA[4], c2aA[4], s2bA[8], c2bA[8];
    float s2aB[4], c2aB[4], s2bB[8], c2bB[8];
#pragma unroll
    for (int i = 0; i < 4; ++i) {
        tw((pb + 4 * i) * 128, w2aA[i], &s2aA[i], &c2aA[i]);
        tw((pb + 4 * i) * 128, w2aB[i], &s2aB[i], &c2aB[i]);
    }
#pragma unroll
    for (int i = 0; i < 8; ++i) {
        tw((pb + 4 * i) * 64, w2bA[i], &s2bA[i], &c2bA[i]);
        tw((pb + 4 * i) * 64, w2bB[i], &s2bB[i], &c2bB[i]);
    }

    // ---- ownership exchange (both tiles, 3 barriers) ----
    exchange2(tA, tB, arA, aiA, arB, aiB, pb, c);

    // ---- phase 2: step 32 (pairs m,m+4) then step 64 (pairs m,m+8) ----
#pragma unroll
    for (int rm = 0; rm < 4; ++rm) {
#pragma unroll
        for (int b = 0; b < 2; ++b) {
            const int mt = b * 8 + rm;
            bf(arA[mt], aiA[mt], arA[mt + 4], aiA[mt + 4], s2aA[rm], c2aA[rm]);
            bf(arB[mt], aiB[mt], arB[mt + 4], aiB[mt + 4], s2aB[rm], c2aB[rm]);
        }
    }
#pragma unroll
    for (int m = 0; m < 8; ++m) {
        bf(arA[m], aiA[m], arA[m + 8], aiA[m + 8], s2bA[m], c2bA[m]);
        bf(arB[m], aiB[m], arB[m + 8], aiB[m + 8], s2bB[m], c2bB[m]);
    }

    // ---- direct stores: rows r0 + pb + 4*m, both tiles ----
#pragma unroll
    for (int m = 0; m < 16; ++m) {
        size_t ro = (size_t)(r0 + pb + 4 * m) * 4096;
        size_t g0 = ro + col0, g1 = ro + col1;
        if (g0 < dst_lim2) dst2[g0] = make_float2(arA[m], aiA[m]);
        if (g1 < dst_lim2) dst2[g1] = make_float2(arB[m], aiB[m]);
    }
}

// Kernel B: stages step=128..4096 on rows {rres + 64*j}. Two column-tiles
// per block, row-major I/O. Grid 2048.
template <int REAL_OUT>
__global__ __launch_bounds__(256) void fft_hi(const float* __restrict__ w,
                                              const float2* __restrict__ src2,
                                              float2* __restrict__ dstc,
                                              float* __restrict__ dstr,
                                              unsigned dst_lim) {
    __shared__ __align__(16) float2 tA[32 * 64];     // 16 KB
    __shared__ __align__(16) float2 tB[32 * 64];     // 16 KB
    const int t    = threadIdx.x;
    const int c    = t & 63;
    const int pb   = t >> 6;
    const int rres = blockIdx.x >> 5;
    const int col0 = ((blockIdx.x & 31) << 7) + c;
    const int col1 = col0 + 64;

    // ---- prefetch ALL w values for both tiles ----
    float wp1A, wp1B, wp2A[2], wp2B[2], wp4A[4], wp4B[4], wp8A[8], wp8B[8];
    {
        size_t ro = (size_t)(rres * 32) * 4096;
        wp1A = w[ro + col0]; wp1B = w[ro + col1];
    }
#pragma unroll
    for (int r = 0; r < 2; ++r) {
        size_t ro = (size_t)((rres + 64 * r) * 16) * 4096;
        wp2A[r] = w[ro + col0]; wp2B[r] = w[ro + col1];
    }
#pragma unroll
    for (int r = 0; r < 4; ++r) {
        size_t ro = (size_t)((rres + 64 * r) * 8) * 4096;
        wp4A[r] = w[ro + col0]; wp4B[r] = w[ro + col1];
    }
#pragma unroll
    for (int r = 0; r < 8; ++r) {
        size_t ro = (size_t)((rres + 64 * r) * 4) * 4096;
        wp8A[r] = w[ro + col0]; wp8B[r] = w[ro + col1];
    }
    float w2aA[4], w2aB[4], w2bA[8], w2bB[8];
#pragma unroll
    for (int i = 0; i < 4; ++i) {
        size_t ro = (size_t)((rres + 64 * (pb + 4 * i)) * 2) * 4096;
        w2aA[i] = w[ro + col0]; w2aB[i] = w[ro + col1];
    }
#pragma unroll
    for (int i = 0; i < 8; ++i) {
        size_t ro = (size_t)(rres + 64 * (pb + 4 * i)) * 4096;
        w2bA[i] = w[ro + col0]; w2bB[i] = w[ro + col1];
    }

    // ---- direct loads: global rows rres + 64*(16*pb+m), both tiles ----
    float arA[16], aiA[16], arB[16], aiB[16];
#pragma unroll
    for (int m = 0; m < 16; ++m) {
        size_t ro = (size_t)(rres + 64 * (16 * pb + m)) * 4096;
        float2 v = src2[ro + col0];
        arA[m] = v.x; aiA[m] = v.y;
        v = src2[ro + col1];
        arB[m] = v.x; aiB[m] = v.y;
    }

    // ---- phase 1: global steps 128, 256, 512, 1024 ----
    {
        float sA, csA, sB, csB;
        tw(rres * 32, wp1A, &sA, &csA);
        tw(rres * 32, wp1B, &sB, &csB);
#pragma unroll
        for (int b = 0; b < 8; ++b) {
            bf(arA[2 * b], aiA[2 * b], arA[2 * b + 1], aiA[2 * b + 1], sA, csA);
            bf(arB[2 * b], aiB[2 * b], arB[2 * b + 1], aiB[2 * b + 1], sB, csB);
        }
    }
#pragma unroll
    for (int r = 0; r < 2; ++r) {
        float sA, csA, sB, csB;
        tw((rres + 64 * r) * 16, wp2A[r], &sA, &csA);
        tw((rres + 64 * r) * 16, wp2B[r], &sB, &csB);
#pragma unroll
        for (int b = 0; b < 4; ++b) {
            const int mt = b * 4 + r;
            bf(arA[mt], aiA[mt], arA[mt + 2], aiA[mt + 2], sA, csA);
            bf(arB[mt], aiB[mt], arB[mt + 2], aiB[mt + 2], sB, csB);
        }
    }
#pragma unroll
    for (int r = 0; r < 4; ++r) {
        float sA, csA, sB, csB;
        tw((rres + 64 * r) * 8, wp4A[r], &sA, &csA);
        tw((rres + 64 * r) * 8, wp4B[r], &sB, &csB);
#pragma unroll
        for (int b = 0; b < 2; ++b) {
            const int mt = b * 8 + r;
            bf(arA[mt], aiA[mt], arA[mt + 4], aiA[mt + 4], sA, csA);
            bf(arB[mt], aiB[mt], arB[mt + 4], aiB[mt + 4], sB, csB);
        }
    }
#pragma unroll
    for (int r = 0; r < 8; ++r) {
        float sA, csA, sB, csB;
        tw((rres + 64 * r) * 4, wp8A[r], &sA, &csA);
        tw((rres + 64 * r) * 4, wp8B[r], &sB, &csB);
        bf(arA[r], aiA[r], arA[r + 8], aiA[r + 8], sA, csA);
        bf(arB[r], aiB[r], arB[r + 8], aiB[r + 8], sB, csB);
    }

    // ---- phase-2 twiddles before the barriers ----
    float s2aA[4], c2aA[4], s2bA[8], c2bA[8];
    float s2aB[4], c2aB[4], s2bB[8], c2bB[8];
#pragma unroll
    for (int i = 0; i < 4; ++i) {
        tw((rres + 64 * (pb + 4 * i)) * 2, w2aA[i], &s2aA[i], &c2aA[i]);
        tw((rres + 64 * (pb + 4 * i)) * 2, w2aB[i], &s2aB[i], &c2aB[i]);
    }
#pragma unroll
    for (int i = 0; i < 8; ++i) {
        tw(rres + 64 * (pb + 4 * i), w2bA[i], &s2bA[i], &c2bA[i]);
        tw(rres + 64 * (pb + 4 * i), w2bB[i], &s2bB[i], &c2bB[i]);
    }

    // ---- ownership exchange (both tiles, 3 barriers) ----
    exchange2(tA, tB, arA, aiA, arB, aiB, pb, c);

    // ---- phase 2: global steps 2048 (m,m+4) and 4096 (m,m+8) ----
#pragma unroll
    for (int rm = 0; rm < 4; ++rm) {
#pragma unroll
        for (int b = 0; b < 2; ++b) {
            const int mt = b * 8 + rm;
            bf(arA[mt], aiA[mt], arA[mt + 4], aiA[mt + 4], s2aA[rm], c2aA[rm]);
            bf(arB[mt], aiB[mt], arB[mt + 4], aiB[mt + 4], s2aB[rm], c2aB[rm]);
        }
    }
#pragma unroll
    for (int m = 0; m < 8; ++m) {
        bf(arA[m], aiA[m], arA[m + 8], aiA[m + 8], s2bA[m], c2bA[m]);
        bf(arB[m], aiB[m], arB[m + 8], aiB[m + 8], s2bB[m], c2bB[m]);
    }

    // ---- stores: rows rres + 64*(pb+4*m), both tiles ----
    if (REAL_OUT) {
#pragma unroll
        for (int m = 0; m < 16; ++m) {
            size_t ro = (size_t)(rres + 64 * (pb + 4 * m)) * 4096;
            size_t g0 = ro + col0, g1 = ro + col1;
            if (g0 < dst_lim) __builtin_nontemporal_store(arA[m], &dstr[g0]);
            if (g1 < dst_lim) __builtin_nontemporal_store(arB[m], &dstr[g1]);
        }
    } else {
#pragma unroll
        for (int m = 0; m < 16; ++m) {
            size_t ro = (size_t)(rres + 64 * (pb + 4 * m)) * 4096;
            size_t g0 = ro + col0, g1 = ro + col1;
            if (g0 < dst_lim) dstc[g0] = make_float2(arA[m], aiA[m]);
            if (g1 < dst_lim) dstc[g1] = make_float2(arB[m], aiB[m]);
        }
    }
}

extern "C" void kernel_launch(void* const* d_in, const int* in_sizes, int n_in,
                              void* d_out, int out_size, void* d_ws, size_t ws_size,
                              hipStream_t stream) {
    const float* x = (const float*)d_in[0];
    const float* w = (const float*)d_in[1];
    const long long NN = 4096LL * 4096LL;

    if ((long long)out_size >= 2 * NN) {
        // d_out = interleaved complex (2*N*N floats): compute in-place.
        float2* o2 = (float2*)d_out;
        unsigned lim2 = (unsigned)(out_size / 2);          // float2 units
        fft_lo<<<2048, 256, 0, stream>>>(x, w, o2, lim2);
        fft_hi<0><<<2048, 256, 0, stream>>>(w, o2, o2, nullptr, lim2);
    } else {
        // Confirmed world: d_out = N*N floats (real part). Complex
        // intermediate in d_ws (>= 2*N*N floats, verified earlier rounds).
        float2* ws2 = (float2*)d_ws;
        unsigned ws_lim2 = (unsigned)(ws_size / 8);        // bytes -> float2 units
        unsigned out_lim = (unsigned)out_size;             // float units
        fft_lo<<<2048, 256, 0, stream>>>(x, w, ws2, ws_lim2);
        fft_hi<1><<<2048, 256, 0, stream>>>(w, (const float2*)ws2, nullptr,
                                            (float*)d_out, out_lim);
    }
}

// Round 7
// 217.596 us; speedup vs baseline: 1.0491x; 1.0491x over previous
//
#include <hip/hip_runtime.h>

#define INV_N (1.0f / 4096.0f)

__device__ __forceinline__ void bf(float& ar, float& ai, float& br, float& bi,
                                   float s, float cs) {
    float tr = cs * br - s * bi;
    float ti = cs * bi + s * br;
    br = ar - tr; bi = ai - ti;
    ar = ar + tr; ai = ai + ti;
}

// Twiddle: angle = -2pi*(k/4096)*wk radians => rev = -(k/4096)*wk revolutions.
__device__ __forceinline__ void tw(int k, float wk, float* s, float* cs) {
    float rev = (float)k * (-INV_N) * wk;
    rev = __builtin_amdgcn_fractf(rev);          // [0,1), handles negatives
    *s  = __builtin_amdgcn_sinf(rev);            // sin(2*pi*rev)
    *cs = __builtin_amdgcn_cosf(rev);            // cos(2*pi*rev)
}

// Wave-local LDS fence: DS ops of a wave execute in order; this waits the
// wave's own LDS ops (lgkmcnt only — prefetched global loads are vmcnt and
// unaffected) and the "memory" clobber stops compiler reordering. No
// cross-wave wait -> no convoy.
#define LDS_FENCE() asm volatile("s_waitcnt lgkmcnt(0)" ::: "memory")

// WAVE-INTERNAL two-round ownership exchange (4 KB per wave, NO barriers).
// Lane layout: cl = lane&15 (column), pb = lane>>4 (row group). The exchange
// moves data between pb-groups at fixed column — entirely within one wave.
// Parity predicate (pb + (m>>2) + (m&3)) & 1: what a lane flushes in a round
// is exactly what it refills in that round (no extra live VGPRs).
// Write slot:  srow = (pb<<3) + ((m>>2)<<1) + ((m&3)>>1)
// Read  slot:  srow = ((m>>2)<<3) + ((m&3)<<1) + (pb>>1)   (row pb+4m's owner)
__device__ __forceinline__ void exchange_w(float2* tp, float (&ar)[16],
                                           float (&ai)[16], int pb, int cl) {
#pragma unroll
    for (int par = 0; par < 2; ++par) {
#pragma unroll
        for (int m = 0; m < 16; ++m) {
            if (((pb + (m >> 2) + (m & 3)) & 1) == par) {
                int srow = (pb << 3) + (((m >> 2) << 1) | ((m & 3) >> 1));
                tp[srow * 16 + cl] = make_float2(ar[m], ai[m]);
            }
        }
        LDS_FENCE();
#pragma unroll
        for (int m = 0; m < 16; ++m) {
            if (((pb + (m >> 2) + (m & 3)) & 1) == par) {
                int srow = ((m >> 2) << 3) + ((m & 3) << 1) + (pb >> 1);
                float2 v = tp[srow * 16 + cl];
                ar[m] = v.x; ai[m] = v.y;
            }
        }
        LDS_FENCE();
    }
}

// Kernel A: stages step=2..64 (butterflies within aligned 64-row blocks).
// 4 independent waves per block, each owning 16 columns; ZERO __syncthreads.
// Direct register I/O, all-w prefetch at entry. Grid 4096.
__global__ __launch_bounds__(256) void fft_lo(const float* __restrict__ x,
                                              const float* __restrict__ w,
                                              float2* __restrict__ dst2,
                                              unsigned dst_lim2) {
    __shared__ __align__(16) float2 tile[4][32 * 16];   // 16 KB, 4 KB/wave
    const int t    = threadIdx.x;
    const int wv   = t >> 6;
    const int lane = t & 63;
    const int cl   = lane & 15;
    const int pb   = lane >> 4;
    const int c0   = (blockIdx.x & 63) << 6;
    const int r0   = (blockIdx.x >> 6) << 6;
    const int src_r0 = r0 ^ 2048;    // initial permutation: new[i] = old[i^2048]
    const int col  = c0 + wv * 16 + cl;

    // ---- prefetch ALL w values (independent of data; overlaps everything) ----
    float wp1[7];
#pragma unroll
    for (int i = 0; i < 7; ++i)
        wp1[i] = w[(size_t)(256 * (i + 1)) * 4096 + col];
    float w2a[4], w2b[8];
#pragma unroll
    for (int i = 0; i < 4; ++i)
        w2a[i] = w[(size_t)((pb + 4 * i) * 128) * 4096 + col];
#pragma unroll
    for (int i = 0; i < 8; ++i)
        w2b[i] = w[(size_t)((pb + 4 * i) * 64) * 4096 + col];

    // ---- direct loads: rows 16*pb+m, imag = 0 (x read once -> nontemporal) ----
    float ar[16], ai[16];
#pragma unroll
    for (int m = 0; m < 16; ++m) {
        ar[m] = __builtin_nontemporal_load(&x[(size_t)(src_r0 + 16 * pb + m) * 4096 + col]);
        ai[m] = 0.f;
    }

    // ---- phase-1 twiddles (7 sincos, k = 256*i; s1[0] = identity) ----
    float s1[8], c1[8];
    s1[0] = 0.f; c1[0] = 1.f;
#pragma unroll
    for (int i = 1; i < 8; ++i)
        tw(256 * i, wp1[i - 1], &s1[i], &c1[i]);

    // ---- phase 1: h = 1,2,4,8 (steps 2..16); twiddle index = r*8/h ----
#pragma unroll
    for (int h = 1; h <= 8; h <<= 1) {
        const int step = h << 1;
#pragma unroll
        for (int r = 0; r < h; ++r) {
            const int ti = r * (8 / h);
            const float s = s1[ti], cs = c1[ti];
#pragma unroll
            for (int b = 0; b < 8 / h; ++b) {
                const int mt = b * step + r;
                bf(ar[mt], ai[mt], ar[mt + h], ai[mt + h], s, cs);
            }
        }
    }

    // ---- phase-2 twiddles (before the exchange; sincos hides under DS ops) ----
    float s2a[4], c2a[4], s2b[8], c2b[8];
#pragma unroll
    for (int i = 0; i < 4; ++i)
        tw((pb + 4 * i) * 128, w2a[i], &s2a[i], &c2a[i]);
#pragma unroll
    for (int i = 0; i < 8; ++i)
        tw((pb + 4 * i) * 64, w2b[i], &s2b[i], &c2b[i]);

    // ---- ownership exchange: wave-internal, barrier-free ----
    exchange_w(&tile[wv][0], ar, ai, pb, cl);

    // ---- phase 2: step 32 (pairs m,m+4) then step 64 (pairs m,m+8) ----
#pragma unroll
    for (int rm = 0; rm < 4; ++rm) {
#pragma unroll
        for (int b = 0; b < 2; ++b) {
            const int mt = b * 8 + rm;
            bf(ar[mt], ai[mt], ar[mt + 4], ai[mt + 4], s2a[rm], c2a[rm]);
        }
    }
#pragma unroll
    for (int m = 0; m < 8; ++m)
        bf(ar[m], ai[m], ar[m + 8], ai[m + 8], s2b[m], c2b[m]);

    // ---- direct stores: rows r0 + pb + 4*m ----
#pragma unroll
    for (int m = 0; m < 16; ++m) {
        size_t gi = (size_t)(r0 + pb + 4 * m) * 4096 + col;
        if (gi < dst_lim2) dst2[gi] = make_float2(ar[m], ai[m]);
    }
}

// Kernel B: stages step=128..4096 on rows {rres + 64*j}. Same wave-independent
// structure, zero barriers. Grid 4096.
template <int REAL_OUT>
__global__ __launch_bounds__(256) void fft_hi(const float* __restrict__ w,
                                              const float2* __restrict__ src2,
                                              float2* __restrict__ dstc,
                                              float* __restrict__ dstr,
                                              unsigned dst_lim) {
    __shared__ __align__(16) float2 tile[4][32 * 16];   // 16 KB, 4 KB/wave
    const int t    = threadIdx.x;
    const int wv   = t >> 6;
    const int lane = t & 63;
    const int cl   = lane & 15;
    const int pb   = lane >> 4;
    const int rres = blockIdx.x >> 6;
    const int col  = ((blockIdx.x & 63) << 6) + wv * 16 + cl;

    // ---- prefetch ALL w values (27 per thread, all independent) ----
    float wp1, wp2[2], wp4[4], wp8[8];
    wp1 = w[(size_t)(rres * 32) * 4096 + col];
#pragma unroll
    for (int r = 0; r < 2; ++r)
        wp2[r] = w[(size_t)((rres + 64 * r) * 16) * 4096 + col];
#pragma unroll
    for (int r = 0; r < 4; ++r)
        wp4[r] = w[(size_t)((rres + 64 * r) * 8) * 4096 + col];
#pragma unroll
    for (int r = 0; r < 8; ++r)
        wp8[r] = w[(size_t)((rres + 64 * r) * 4) * 4096 + col];
    float w2a[4], w2b[8];
#pragma unroll
    for (int i = 0; i < 4; ++i)
        w2a[i] = w[(size_t)((rres + 64 * (pb + 4 * i)) * 2) * 4096 + col];
#pragma unroll
    for (int i = 0; i < 8; ++i)
        w2b[i] = w[(size_t)(rres + 64 * (pb + 4 * i)) * 4096 + col];

    // ---- direct loads: global rows rres + 64*(16*pb+m) ----
    float ar[16], ai[16];
#pragma unroll
    for (int m = 0; m < 16; ++m) {
        float2 v = src2[(size_t)(rres + 64 * (16 * pb + m)) * 4096 + col];
        ar[m] = v.x; ai[m] = v.y;
    }

    // ---- phase 1: global steps 128, 256, 512, 1024 ----
    {
        float s, cs;
        tw(rres * 32, wp1, &s, &cs);
#pragma unroll
        for (int b = 0; b < 8; ++b)
            bf(ar[2 * b], ai[2 * b], ar[2 * b + 1], ai[2 * b + 1], s, cs);
    }
#pragma unroll
    for (int r = 0; r < 2; ++r) {
        float s, cs;
        tw((rres + 64 * r) * 16, wp2[r], &s, &cs);
#pragma unroll
        for (int b = 0; b < 4; ++b) {
            const int mt = b * 4 + r;
            bf(ar[mt], ai[mt], ar[mt + 2], ai[mt + 2], s, cs);
        }
    }
#pragma unroll
    for (int r = 0; r < 4; ++r) {
        float s, cs;
        tw((rres + 64 * r) * 8, wp4[r], &s, &cs);
#pragma unroll
        for (int b = 0; b < 2; ++b) {
            const int mt = b * 8 + r;
            bf(ar[mt], ai[mt], ar[mt + 4], ai[mt + 4], s, cs);
        }
    }
#pragma unroll
    for (int r = 0; r < 8; ++r) {
        float s, cs;
        tw((rres + 64 * r) * 4, wp8[r], &s, &cs);
        bf(ar[r], ai[r], ar[r + 8], ai[r + 8], s, cs);
    }

    // ---- phase-2 twiddles (before the exchange) ----
    float s2a[4], c2a[4], s2b[8], c2b[8];
#pragma unroll
    for (int i = 0; i < 4; ++i)
        tw((rres + 64 * (pb + 4 * i)) * 2, w2a[i], &s2a[i], &c2a[i]);
#pragma unroll
    for (int i = 0; i < 8; ++i)
        tw(rres + 64 * (pb + 4 * i), w2b[i], &s2b[i], &c2b[i]);

    // ---- ownership exchange: wave-internal, barrier-free ----
    exchange_w(&tile[wv][0], ar, ai, pb, cl);

    // ---- phase 2: global steps 2048 (m,m+4) and 4096 (m,m+8) ----
#pragma unroll
    for (int rm = 0; rm < 4; ++rm) {
#pragma unroll
        for (int b = 0; b < 2; ++b) {
            const int mt = b * 8 + rm;
            bf(ar[mt], ai[mt], ar[mt + 4], ai[mt + 4], s2a[rm], c2a[rm]);
        }
    }
#pragma unroll
    for (int m = 0; m < 8; ++m)
        bf(ar[m], ai[m], ar[m + 8], ai[m + 8], s2b[m], c2b[m]);

    // ---- stores: rows rres + 64*(pb+4*m), row-major output ----
    if (REAL_OUT) {
#pragma unroll
        for (int m = 0; m < 16; ++m) {
            size_t gi = (size_t)(rres + 64 * (pb + 4 * m)) * 4096 + col;
            if (gi < dst_lim) __builtin_nontemporal_store(ar[m], &dstr[gi]);
        }
    } else {
#pragma unroll
        for (int m = 0; m < 16; ++m) {
            size_t gi = (size_t)(rres + 64 * (pb + 4 * m)) * 4096 + col;
            if (gi < dst_lim) dstc[gi] = make_float2(ar[m], ai[m]);
        }
    }
}

extern "C" void kernel_launch(void* const* d_in, const int* in_sizes, int n_in,
                              void* d_out, int out_size, void* d_ws, size_t ws_size,
                              hipStream_t stream) {
    const float* x = (const float*)d_in[0];
    const float* w = (const float*)d_in[1];
    const long long NN = 4096LL * 4096LL;

    if ((long long)out_size >= 2 * NN) {
        // d_out = interleaved complex (2*N*N floats): compute in-place.
        float2* o2 = (float2*)d_out;
        unsigned lim2 = (unsigned)(out_size / 2);          // float2 units
        fft_lo<<<4096, 256, 0, stream>>>(x, w, o2, lim2);
        fft_hi<0><<<4096, 256, 0, stream>>>(w, o2, o2, nullptr, lim2);
    } else {
        // Confirmed world: d_out = N*N floats (real part). Complex
        // intermediate in d_ws (>= 2*N*N floats, verified earlier rounds).
        float2* ws2 = (float2*)d_ws;
        unsigned ws_lim2 = (unsigned)(ws_size / 8);        // bytes -> float2 units
        unsigned out_lim = (unsigned)out_size;             // float units
        fft_lo<<<4096, 256, 0, stream>>>(x, w, ws2, ws_lim2);
        fft_hi<1><<<4096, 256, 0, stream>>>(w, (const float2*)ws2, nullptr,
                                            (float*)d_out, out_lim);
    }
}

// Round 8
// 200.481 us; speedup vs baseline: 1.1386x; 1.0854x over previous
//
#include <hip/hip_runtime.h>

#define INV_N (1.0f / 4096.0f)

__device__ __forceinline__ void bf(float& ar, float& ai, float& br, float& bi,
                                   float s, float cs) {
    float tr = cs * br - s * bi;
    float ti = cs * bi + s * br;
    br = ar - tr; bi = ai - ti;
    ar = ar + tr; ai = ai + ti;
}

// Twiddle: angle = -2pi*(k/4096)*wk radians => rev = -(k/4096)*wk revolutions.
__device__ __forceinline__ void tw(int k, float wk, float* s, float* cs) {
    float rev = (float)k * (-INV_N) * wk;
    rev = __builtin_amdgcn_fractf(rev);          // [0,1), handles negatives
    *s  = __builtin_amdgcn_sinf(rev);            // sin(2*pi*rev)
    *cs = __builtin_amdgcn_cosf(rev);            // cos(2*pi*rev)
}

// Two-round 16 KB ownership exchange: consecutive-16 rows -> stride-4 rows.
// Parity predicate (pb + (m>>2) + (m&3)) & 1: what a thread flushes in a
// round is exactly what it refills in that round (no extra live VGPRs).
__device__ __forceinline__ void exchange(float2* tile, float (&ar)[16],
                                         float (&ai)[16], int pb, int c) {
#pragma unroll
    for (int par = 0; par < 2; ++par) {
#pragma unroll
        for (int m = 0; m < 16; ++m) {
            if (((pb + (m >> 2) + (m & 3)) & 1) == par) {
                int srow = (pb << 3) + (((m >> 2) << 1) | ((m & 3) >> 1));
                tile[srow * 64 + c] = make_float2(ar[m], ai[m]);
            }
        }
        __syncthreads();
#pragma unroll
        for (int m = 0; m < 16; ++m) {
            if (((pb + (m >> 2) + (m & 3)) & 1) == par) {
                int srow = ((m >> 2) << 3) + ((m & 3) << 1) + (pb >> 1);
                float2 v = tile[srow * 64 + c];
                ar[m] = v.x; ai[m] = v.y;
            }
        }
        if (par == 0) __syncthreads();
    }
}

// Kernel A: stages step=2..64 (butterflies within aligned 64-row blocks).
// Load issue order (vmcnt is FIFO): DATA first, phase-1 w second, phase-2 w
// LAST — phase-1 compute then waits only on data+wp1; the 12 phase-2 w loads
// resolve in flight under phase-1 compute + the exchange barriers.
// All global indices are 32-bit unsigned (offsets < 2^27 B): sgpr-base +
// 32-bit voffset addressing, less address VALU.
__global__ __launch_bounds__(256) void fft_lo(const float* __restrict__ x,
                                              const float* __restrict__ w,
                                              float2* __restrict__ dst2,
                                              unsigned dst_lim2) {
    __shared__ __align__(16) float2 tile[32 * 64];   // 16 KB, exchange only
    const int t   = threadIdx.x;
    const int c   = t & 63;
    const int pb  = t >> 6;
    const int c0  = (blockIdx.x & 63) << 6;
    const int r0  = (blockIdx.x >> 6) << 6;
    const int src_r0 = r0 ^ 2048;      // initial permutation: new[i] = old[i^2048]
    const unsigned col = (unsigned)(c0 + c);

    // ---- 1) data loads FIRST: rows 16*pb+m, imag = 0 (x read once -> nt) ----
    float ar[16], ai[16];
#pragma unroll
    for (int m = 0; m < 16; ++m) {
        unsigned gi = (unsigned)(src_r0 + 16 * pb + m) * 4096u + col;
        ar[m] = __builtin_nontemporal_load(&x[gi]);
        ai[m] = 0.f;
    }

    // ---- 2) phase-1 w (7 loads, k = 256*i) ----
    float wp1[7];
#pragma unroll
    for (int i = 0; i < 7; ++i)
        wp1[i] = w[(unsigned)(256 * (i + 1)) * 4096u + col];

    // ---- 3) phase-2 w LAST (12 loads; overlap with phase-1 compute) ----
    float w2a[4], w2b[8];
#pragma unroll
    for (int i = 0; i < 4; ++i)
        w2a[i] = w[(unsigned)((pb + 4 * i) * 128) * 4096u + col];
#pragma unroll
    for (int i = 0; i < 8; ++i)
        w2b[i] = w[(unsigned)((pb + 4 * i) * 64) * 4096u + col];

    // ---- phase-1 twiddles (7 sincos; s1[0] = identity) ----
    float s1[8], c1[8];
    s1[0] = 0.f; c1[0] = 1.f;
#pragma unroll
    for (int i = 1; i < 8; ++i)
        tw(256 * i, wp1[i - 1], &s1[i], &c1[i]);

    // ---- phase 1: h = 1,2,4,8 (steps 2..16); twiddle index = r*8/h ----
#pragma unroll
    for (int h = 1; h <= 8; h <<= 1) {
        const int step = h << 1;
#pragma unroll
        for (int r = 0; r < h; ++r) {
            const int ti = r * (8 / h);
            const float s = s1[ti], cs = c1[ti];
#pragma unroll
            for (int b = 0; b < 8 / h; ++b) {
                const int mt = b * step + r;
                bf(ar[mt], ai[mt], ar[mt + h], ai[mt + h], s, cs);
            }
        }
    }

    // ---- phase-2 twiddles (w2a/w2b have had phase-1 to land) ----
    float s2a[4], c2a[4], s2b[8], c2b[8];
#pragma unroll
    for (int i = 0; i < 4; ++i)
        tw((pb + 4 * i) * 128, w2a[i], &s2a[i], &c2a[i]);
#pragma unroll
    for (int i = 0; i < 8; ++i)
        tw((pb + 4 * i) * 64, w2b[i], &s2b[i], &c2b[i]);

    // ---- ownership exchange: consecutive-16 -> stride-4 (16 KB, 3 barriers) --
    exchange(tile, ar, ai, pb, c);

    // ---- phase 2: step 32 (pairs m,m+4) then step 64 (pairs m,m+8) ----
#pragma unroll
    for (int rm = 0; rm < 4; ++rm) {
#pragma unroll
        for (int b = 0; b < 2; ++b) {
            const int mt = b * 8 + rm;
            bf(ar[mt], ai[mt], ar[mt + 4], ai[mt + 4], s2a[rm], c2a[rm]);
        }
    }
#pragma unroll
    for (int m = 0; m < 8; ++m)
        bf(ar[m], ai[m], ar[m + 8], ai[m + 8], s2b[m], c2b[m]);

    // ---- direct stores: rows r0 + pb + 4*m (512 B/wave, coalesced) ----
#pragma unroll
    for (int m = 0; m < 16; ++m) {
        unsigned gi = (unsigned)(r0 + pb + 4 * m) * 4096u + col;
        if (gi < dst_lim2) dst2[gi] = make_float2(ar[m], ai[m]);
    }
}

// Kernel B: stages step=128..4096 on rows {rres + 64*j}. Same ordering rules.
template <int REAL_OUT>
__global__ __launch_bounds__(256) void fft_hi(const float* __restrict__ w,
                                              const float2* __restrict__ src2,
                                              float2* __restrict__ dstc,
                                              float* __restrict__ dstr,
                                              unsigned dst_lim) {
    __shared__ __align__(16) float2 tile[32 * 64];   // 16 KB, exchange only
    const int t    = threadIdx.x;
    const int c    = t & 63;
    const int pb   = t >> 6;
    const int rres = blockIdx.x >> 6;
    const unsigned col = (unsigned)(((blockIdx.x & 63) << 6) + c);

    // ---- 1) data loads FIRST: global rows rres + 64*(16*pb+m) ----
    float ar[16], ai[16];
#pragma unroll
    for (int m = 0; m < 16; ++m) {
        unsigned gi = (unsigned)(rres + 64 * (16 * pb + m)) * 4096u + col;
        float2 v = src2[gi];
        ar[m] = v.x; ai[m] = v.y;
    }

    // ---- 2) phase-1 w (15 loads) ----
    float wp1, wp2[2], wp4[4], wp8[8];
    wp1 = w[(unsigned)(rres * 32) * 4096u + col];
#pragma unroll
    for (int r = 0; r < 2; ++r)
        wp2[r] = w[(unsigned)((rres + 64 * r) * 16) * 4096u + col];
#pragma unroll
    for (int r = 0; r < 4; ++r)
        wp4[r] = w[(unsigned)((rres + 64 * r) * 8) * 4096u + col];
#pragma unroll
    for (int r = 0; r < 8; ++r)
        wp8[r] = w[(unsigned)((rres + 64 * r) * 4) * 4096u + col];

    // ---- 3) phase-2 w LAST (12 loads; overlap with phase-1 compute) ----
    float w2a[4], w2b[8];
#pragma unroll
    for (int i = 0; i < 4; ++i)
        w2a[i] = w[(unsigned)((rres + 64 * (pb + 4 * i)) * 2) * 4096u + col];
#pragma unroll
    for (int i = 0; i < 8; ++i)
        w2b[i] = w[(unsigned)(rres + 64 * (pb + 4 * i)) * 4096u + col];

    // ---- phase 1: global steps 128, 256, 512, 1024 ----
    {
        float s, cs;
        tw(rres * 32, wp1, &s, &cs);
#pragma unroll
        for (int b = 0; b < 8; ++b)
            bf(ar[2 * b], ai[2 * b], ar[2 * b + 1], ai[2 * b + 1], s, cs);
    }
#pragma unroll
    for (int r = 0; r < 2; ++r) {
        float s, cs;
        tw((rres + 64 * r) * 16, wp2[r], &s, &cs);
#pragma unroll
        for (int b = 0; b < 4; ++b) {
            const int mt = b * 4 + r;
            bf(ar[mt], ai[mt], ar[mt + 2], ai[mt + 2], s, cs);
        }
    }
#pragma unroll
    for (int r = 0; r < 4; ++r) {
        float s, cs;
        tw((rres + 64 * r) * 8, wp4[r], &s, &cs);
#pragma unroll
        for (int b = 0; b < 2; ++b) {
            const int mt = b * 8 + r;
            bf(ar[mt], ai[mt], ar[mt + 4], ai[mt + 4], s, cs);
        }
    }
#pragma unroll
    for (int r = 0; r < 8; ++r) {
        float s, cs;
        tw((rres + 64 * r) * 4, wp8[r], &s, &cs);
        bf(ar[r], ai[r], ar[r + 8], ai[r + 8], s, cs);
    }

    // ---- phase-2 twiddles (w2a/w2b have had phase-1 to land) ----
    float s2a[4], c2a[4], s2b[8], c2b[8];
#pragma unroll
    for (int i = 0; i < 4; ++i)
        tw((rres + 64 * (pb + 4 * i)) * 2, w2a[i], &s2a[i], &c2a[i]);
#pragma unroll
    for (int i = 0; i < 8; ++i)
        tw(rres + 64 * (pb + 4 * i), w2b[i], &s2b[i], &c2b[i]);

    // ---- ownership exchange (16 KB, 3 barriers) ----
    exchange(tile, ar, ai, pb, c);

    // ---- phase 2: global steps 2048 (m,m+4) and 4096 (m,m+8) ----
#pragma unroll
    for (int rm = 0; rm < 4; ++rm) {
#pragma unroll
        for (int b = 0; b < 2; ++b) {
            const int mt = b * 8 + rm;
            bf(ar[mt], ai[mt], ar[mt + 4], ai[mt + 4], s2a[rm], c2a[rm]);
        }
    }
#pragma unroll
    for (int m = 0; m < 8; ++m)
        bf(ar[m], ai[m], ar[m + 8], ai[m + 8], s2b[m], c2b[m]);

    // ---- stores: rows rres + 64*(pb+4*m), row-major output ----
    if (REAL_OUT) {
#pragma unroll
        for (int m = 0; m < 16; ++m) {
            unsigned gi = (unsigned)(rres + 64 * (pb + 4 * m)) * 4096u + col;
            if (gi < dst_lim) __builtin_nontemporal_store(ar[m], &dstr[gi]);
        }
    } else {
#pragma unroll
        for (int m = 0; m < 16; ++m) {
            unsigned gi = (unsigned)(rres + 64 * (pb + 4 * m)) * 4096u + col;
            if (gi < dst_lim) dstc[gi] = make_float2(ar[m], ai[m]);
        }
    }
}

extern "C" void kernel_launch(void* const* d_in, const int* in_sizes, int n_in,
                              void* d_out, int out_size, void* d_ws, size_t ws_size,
                              hipStream_t stream) {
    const float* x = (const float*)d_in[0];
    const float* w = (const float*)d_in[1];
    const long long NN = 4096LL * 4096LL;

    if ((long long)out_size >= 2 * NN) {
        // d_out = interleaved complex (2*N*N floats): compute in-place.
        float2* o2 = (float2*)d_out;
        unsigned lim2 = (unsigned)(out_size / 2);          // float2 units
        fft_lo<<<4096, 256, 0, stream>>>(x, w, o2, lim2);
        fft_hi<0><<<4096, 256, 0, stream>>>(w, o2, o2, nullptr, lim2);
    } else {
        // Confirmed world: d_out = N*N floats (real part). Complex
        // intermediate in d_ws (>= 2*N*N floats, verified earlier rounds).
        float2* ws2 = (float2*)d_ws;
        unsigned ws_lim2 = (unsigned)(ws_size / 8);        // bytes -> float2 units
        unsigned out_lim = (unsigned)out_size;             // float units
        fft_lo<<<4096, 256, 0, stream>>>(x, w, ws2, ws_lim2);
        fft_hi<1><<<4096, 256, 0, stream>>>(w, (const float2*)ws2, nullptr,
                                            (float*)d_out, out_lim);
    }
}

// Round 9
// 198.950 us; speedup vs baseline: 1.1474x; 1.0077x over previous
//
#include <hip/hip_runtime.h>

#define INV_N (1.0f / 4096.0f)

__device__ __forceinline__ void bf(float& ar, float& ai, float& br, float& bi,
                                   float s, float cs) {
    float tr = cs * br - s * bi;
    float ti = cs * bi + s * br;
    br = ar - tr; bi = ai - ti;
    ar = ar + tr; ai = ai + ti;
}

// Twiddle: angle = -2pi*(k/4096)*wk radians => rev = -(k/4096)*wk revolutions.
__device__ __forceinline__ void tw(int k, float wk, float* s, float* cs) {
    float rev = (float)k * (-INV_N) * wk;
    rev = __builtin_amdgcn_fractf(rev);          // [0,1), handles negatives
    *s  = __builtin_amdgcn_sinf(rev);            // sin(2*pi*rev)
    *cs = __builtin_amdgcn_cosf(rev);            // cos(2*pi*rev)
}

// Two-round 16 KB ownership exchange: consecutive-16 rows -> stride-4 rows.
// Parity predicate (pb + (m>>2) + (m&3)) & 1: what a thread flushes in a
// round is exactly what it refills in that round (no extra live VGPRs).
__device__ __forceinline__ void exchange(float2* tile, float (&ar)[16],
                                         float (&ai)[16], int pb, int c) {
#pragma unroll
    for (int par = 0; par < 2; ++par) {
#pragma unroll
        for (int m = 0; m < 16; ++m) {
            if (((pb + (m >> 2) + (m & 3)) & 1) == par) {
                int srow = (pb << 3) + (((m >> 2) << 1) | ((m & 3) >> 1));
                tile[srow * 64 + c] = make_float2(ar[m], ai[m]);
            }
        }
        __syncthreads();
#pragma unroll
        for (int m = 0; m < 16; ++m) {
            if (((pb + (m >> 2) + (m & 3)) & 1) == par) {
                int srow = ((m >> 2) << 3) + ((m & 3) << 1) + (pb >> 1);
                float2 v = tile[srow * 64 + c];
                ar[m] = v.x; ai[m] = v.y;
            }
        }
        if (par == 0) __syncthreads();
    }
}

// Kernel A: stages step=2..64. TWO-HALF PIPELINE: stages h=1,2,4 pair rows
// only within each 8-row half; h=8 crosses. Issue order: rows0-7, even-s1 w,
// rows8-15, odd-s1 w, phase-2 w. Half-A compute gates on load #11 of 43 —
// the rest of the convoy drains under compute (graduated vmcnt).
__global__ __launch_bounds__(256) void fft_lo(const float* __restrict__ x,
                                              const float* __restrict__ w,
                                              float2* __restrict__ dst2,
                                              unsigned dst_lim2) {
    __shared__ __align__(16) float2 tile[32 * 64];   // 16 KB, exchange only
    const int t   = threadIdx.x;
    const int c   = t & 63;
    const int pb  = t >> 6;
    const int c0  = (blockIdx.x & 63) << 6;
    const int r0  = (blockIdx.x >> 6) << 6;
    const int src_r0 = r0 ^ 2048;      // initial permutation: new[i] = old[i^2048]
    const unsigned col = (unsigned)(c0 + c);

    float ar[16], ai[16];
    // ---- 1) data rows 0..7 ----
#pragma unroll
    for (int m = 0; m < 8; ++m) {
        unsigned gi = (unsigned)(src_r0 + 16 * pb + m) * 4096u + col;
        ar[m] = __builtin_nontemporal_load(&x[gi]);
        ai[m] = 0.f;
    }
    // ---- 2) w for half-stage twiddles s1[2],s1[4],s1[6] (k=512,1024,1536) ----
    float wpe[3];
#pragma unroll
    for (int i = 0; i < 3; ++i)
        wpe[i] = w[(unsigned)(512 * (i + 1)) * 4096u + col];
    // ---- 3) data rows 8..15 ----
#pragma unroll
    for (int m = 8; m < 16; ++m) {
        unsigned gi = (unsigned)(src_r0 + 16 * pb + m) * 4096u + col;
        ar[m] = __builtin_nontemporal_load(&x[gi]);
        ai[m] = 0.f;
    }
    // ---- 4) w for cross-stage twiddles s1[1,3,5,7] (k=256,768,1280,1792) ----
    float wpo[4];
#pragma unroll
    for (int i = 0; i < 4; ++i)
        wpo[i] = w[(unsigned)(256 * (2 * i + 1)) * 4096u + col];
    // ---- 5) phase-2 w LAST ----
    float w2a[4], w2b[8];
#pragma unroll
    for (int i = 0; i < 4; ++i)
        w2a[i] = w[(unsigned)((pb + 4 * i) * 128) * 4096u + col];
#pragma unroll
    for (int i = 0; i < 8; ++i)
        w2b[i] = w[(unsigned)((pb + 4 * i) * 64) * 4096u + col];

    // ---- even twiddles (gate: rows0-7 + wpe = 11 loads) ----
    float s1[8], c1[8];
    s1[0] = 0.f; c1[0] = 1.f;
    tw(512,  wpe[0], &s1[2], &c1[2]);
    tw(1024, wpe[1], &s1[4], &c1[4]);
    tw(1536, wpe[2], &s1[6], &c1[6]);

    // ---- half stages h=1,2,4 on each half (A gates early; B drains mid) ----
#pragma unroll
    for (int base = 0; base <= 8; base += 8) {
#pragma unroll
        for (int b = 0; b < 4; ++b)          // h=1, identity
            bf(ar[base + 2 * b], ai[base + 2 * b],
               ar[base + 2 * b + 1], ai[base + 2 * b + 1], 0.f, 1.f);
#pragma unroll
        for (int r = 0; r < 2; ++r)          // h=2, ti=4r
#pragma unroll
            for (int b = 0; b < 2; ++b) {
                int mt = base + b * 4 + r;
                bf(ar[mt], ai[mt], ar[mt + 2], ai[mt + 2], s1[4 * r], c1[4 * r]);
            }
#pragma unroll
        for (int r = 0; r < 4; ++r) {        // h=4, ti=2r
            int mt = base + r;
            bf(ar[mt], ai[mt], ar[mt + 4], ai[mt + 4], s1[2 * r], c1[2 * r]);
        }
    }

    // ---- odd twiddles (gate: +wpo) then cross stage h=8 ----
    tw(256,  wpo[0], &s1[1], &c1[1]);
    tw(768,  wpo[1], &s1[3], &c1[3]);
    tw(1280, wpo[2], &s1[5], &c1[5]);
    tw(1792, wpo[3], &s1[7], &c1[7]);
#pragma unroll
    for (int r = 0; r < 8; ++r)
        bf(ar[r], ai[r], ar[r + 8], ai[r + 8], s1[r], c1[r]);

    // ---- phase-2 twiddles (gate: full convoy — had max time to drain) ----
    float s2a[4], c2a[4], s2b[8], c2b[8];
#pragma unroll
    for (int i = 0; i < 4; ++i)
        tw((pb + 4 * i) * 128, w2a[i], &s2a[i], &c2a[i]);
#pragma unroll
    for (int i = 0; i < 8; ++i)
        tw((pb + 4 * i) * 64, w2b[i], &s2b[i], &c2b[i]);

    // ---- ownership exchange (16 KB, 3 barriers) ----
    exchange(tile, ar, ai, pb, c);

    // ---- phase 2: step 32 (pairs m,m+4) then step 64 (pairs m,m+8) ----
#pragma unroll
    for (int rm = 0; rm < 4; ++rm) {
#pragma unroll
        for (int b = 0; b < 2; ++b) {
            const int mt = b * 8 + rm;
            bf(ar[mt], ai[mt], ar[mt + 4], ai[mt + 4], s2a[rm], c2a[rm]);
        }
    }
#pragma unroll
    for (int m = 0; m < 8; ++m)
        bf(ar[m], ai[m], ar[m + 8], ai[m + 8], s2b[m], c2b[m]);

    // ---- direct stores: rows r0 + pb + 4*m ----
#pragma unroll
    for (int m = 0; m < 16; ++m) {
        unsigned gi = (unsigned)(r0 + pb + 4 * m) * 4096u + col;
        if (gi < dst_lim2) dst2[gi] = make_float2(ar[m], ai[m]);
    }
}

// Kernel B: stages step=128..4096. Same two-half pipeline: h=1,2,4 are
// half-local (twiddles wp1/wp2/wp4 shared by both halves), h=8 crosses (wp8).
template <int REAL_OUT>
__global__ __launch_bounds__(256) void fft_hi(const float* __restrict__ w,
                                              const float2* __restrict__ src2,
                                              float2* __restrict__ dstc,
                                              float* __restrict__ dstr,
                                              unsigned dst_lim) {
    __shared__ __align__(16) float2 tile[32 * 64];   // 16 KB, exchange only
    const int t    = threadIdx.x;
    const int c    = t & 63;
    const int pb   = t >> 6;
    const int rres = blockIdx.x >> 6;
    const unsigned col = (unsigned)(((blockIdx.x & 63) << 6) + c);

    float ar[16], ai[16];
    // ---- 1) data rows 0..7 ----
#pragma unroll
    for (int m = 0; m < 8; ++m) {
        unsigned gi = (unsigned)(rres + 64 * (16 * pb + m)) * 4096u + col;
        float2 v = src2[gi];
        ar[m] = v.x; ai[m] = v.y;
    }
    // ---- 2) w for half stages h=1,2,4 (7 loads) ----
    float wp1, wp2[2], wp4[4];
    wp1 = w[(unsigned)(rres * 32) * 4096u + col];
#pragma unroll
    for (int r = 0; r < 2; ++r)
        wp2[r] = w[(unsigned)((rres + 64 * r) * 16) * 4096u + col];
#pragma unroll
    for (int r = 0; r < 4; ++r)
        wp4[r] = w[(unsigned)((rres + 64 * r) * 8) * 4096u + col];
    // ---- 3) data rows 8..15 ----
#pragma unroll
    for (int m = 8; m < 16; ++m) {
        unsigned gi = (unsigned)(rres + 64 * (16 * pb + m)) * 4096u + col;
        float2 v = src2[gi];
        ar[m] = v.x; ai[m] = v.y;
    }
    // ---- 4) w for cross stage h=8 (8 loads) ----
    float wp8[8];
#pragma unroll
    for (int r = 0; r < 8; ++r)
        wp8[r] = w[(unsigned)((rres + 64 * r) * 4) * 4096u + col];
    // ---- 5) phase-2 w LAST (12 loads) ----
    float w2a[4], w2b[8];
#pragma unroll
    for (int i = 0; i < 4; ++i)
        w2a[i] = w[(unsigned)((rres + 64 * (pb + 4 * i)) * 2) * 4096u + col];
#pragma unroll
    for (int i = 0; i < 8; ++i)
        w2b[i] = w[(unsigned)(rres + 64 * (pb + 4 * i)) * 4096u + col];

    // ---- half-stage twiddles (gate: rows0-7 + 7 w = 15 of 43 loads) ----
    float st1, ct1, st2[2], ct2[2], st4[4], ct4[4];
    tw(rres * 32, wp1, &st1, &ct1);
#pragma unroll
    for (int r = 0; r < 2; ++r)
        tw((rres + 64 * r) * 16, wp2[r], &st2[r], &ct2[r]);
#pragma unroll
    for (int r = 0; r < 4; ++r)
        tw((rres + 64 * r) * 8, wp4[r], &st4[r], &ct4[r]);

    // ---- half stages h=1,2,4 on each half ----
#pragma unroll
    for (int base = 0; base <= 8; base += 8) {
#pragma unroll
        for (int b = 0; b < 4; ++b)          // h=1 (global step 128)
            bf(ar[base + 2 * b], ai[base + 2 * b],
               ar[base + 2 * b + 1], ai[base + 2 * b + 1], st1, ct1);
#pragma unroll
        for (int r = 0; r < 2; ++r)          // h=2 (step 256)
#pragma unroll
            for (int b = 0; b < 2; ++b) {
                int mt = base + b * 4 + r;
                bf(ar[mt], ai[mt], ar[mt + 2], ai[mt + 2], st2[r], ct2[r]);
            }
#pragma unroll
        for (int r = 0; r < 4; ++r) {        // h=4 (step 512)
            int mt = base + r;
            bf(ar[mt], ai[mt], ar[mt + 4], ai[mt + 4], st4[r], ct4[r]);
        }
    }

    // ---- cross-stage twiddles then h=8 (global step 1024) ----
#pragma unroll
    for (int r = 0; r < 8; ++r) {
        float s, cs;
        tw((rres + 64 * r) * 4, wp8[r], &s, &cs);
        bf(ar[r], ai[r], ar[r + 8], ai[r + 8], s, cs);
    }

    // ---- phase-2 twiddles (gate: full convoy) ----
    float s2a[4], c2a[4], s2b[8], c2b[8];
#pragma unroll
    for (int i = 0; i < 4; ++i)
        tw((rres + 64 * (pb + 4 * i)) * 2, w2a[i], &s2a[i], &c2a[i]);
#pragma unroll
    for (int i = 0; i < 8; ++i)
        tw(rres + 64 * (pb + 4 * i), w2b[i], &s2b[i], &c2b[i]);

    // ---- ownership exchange (16 KB, 3 barriers) ----
    exchange(tile, ar, ai, pb, c);

    // ---- phase 2: global steps 2048 (m,m+4) and 4096 (m,m+8) ----
#pragma unroll
    for (int rm = 0; rm < 4; ++rm) {
#pragma unroll
        for (int b = 0; b < 2; ++b) {
            const int mt = b * 8 + rm;
            bf(ar[mt], ai[mt], ar[mt + 4], ai[mt + 4], s2a[rm], c2a[rm]);
        }
    }
#pragma unroll
    for (int m = 0; m < 8; ++m)
        bf(ar[m], ai[m], ar[m + 8], ai[m + 8], s2b[m], c2b[m]);

    // ---- stores: rows rres + 64*(pb+4*m), row-major output ----
    if (REAL_OUT) {
#pragma unroll
        for (int m = 0; m < 16; ++m) {
            unsigned gi = (unsigned)(rres + 64 * (pb + 4 * m)) * 4096u + col;
            if (gi < dst_lim) __builtin_nontemporal_store(ar[m], &dstr[gi]);
        }
    } else {
#pragma unroll
        for (int m = 0; m < 16; ++m) {
            unsigned gi = (unsigned)(rres + 64 * (pb + 4 * m)) * 4096u + col;
            if (gi < dst_lim) dstc[gi] = make_float2(ar[m], ai[m]);
        }
    }
}

extern "C" void kernel_launch(void* const* d_in, const int* in_sizes, int n_in,
                              void* d_out, int out_size, void* d_ws, size_t ws_size,
                              hipStream_t stream) {
    const float* x = (const float*)d_in[0];
    const float* w = (const float*)d_in[1];
    const long long NN = 4096LL * 4096LL;

    if ((long long)out_size >= 2 * NN) {
        // d_out = interleaved complex (2*N*N floats): compute in-place.
        float2* o2 = (float2*)d_out;
        unsigned lim2 = (unsigned)(out_size / 2);          // float2 units
        fft_lo<<<4096, 256, 0, stream>>>(x, w, o2, lim2);
        fft_hi<0><<<4096, 256, 0, stream>>>(w, o2, o2, nullptr, lim2);
    } else {
        // Confirmed world: d_out = N*N floats (real part). Complex
        // intermediate in d_ws (>= 2*N*N floats, verified earlier rounds).
        float2* ws2 = (float2*)d_ws;
        unsigned ws_lim2 = (unsigned)(ws_size / 8);        // bytes -> float2 units
        unsigned out_lim = (unsigned)out_size;             // float units
        fft_lo<<<4096, 256, 0, stream>>>(x, w, ws2, ws_lim2);
        fft_hi<1><<<4096, 256, 0, stream>>>(w, (const float2*)ws2, nullptr,
                                            (float*)d_out, out_lim);
    }
}